// Round 1
// baseline (1412.879 us; speedup 1.0000x reference)
//
#include <hip/hip_runtime.h>
#include <hip/hip_fp16.h>

#define B_  256
#define T_  2048
#define D_  128
#define H_  128
#define CH  32
#define NCH (T_ / CH)
#define XGP (4 * H_ + 8)                 // xgf padded row: +16B breaks 4-way bank conflict

#define NLOG2E  (-1.4426950408889634f)   // i,f,o rows: sigm(x)=rcp(1+exp2(x*NLOG2E))
#define LOG2E2  ( 2.8853900817779268f)   // g rows:    tanh(x)=1-2*rcp(1+exp2(x*LOG2E2))

typedef __attribute__((ext_vector_type(8))) _Float16 half8v;
typedef __attribute__((ext_vector_type(2))) _Float16 half2v;
typedef __attribute__((ext_vector_type(4))) float    floatx4;

static __device__ __forceinline__ unsigned pkh(float a, float b) {
  return __builtin_bit_cast(unsigned, __builtin_amdgcn_cvt_pkrtz(a, b));
}
static __device__ __forceinline__ float h2f_lo(unsigned u) {
  return __half2float(__ushort_as_half((unsigned short)(u & 0xffffu)));
}
static __device__ __forceinline__ float h2f_hi(unsigned u) {
  return __half2float(__ushort_as_half((unsigned short)(u >> 16)));
}
// full-rate f16 dot2 with f32 accumulate: c += h.x*w.x + h.y*w.y
static __device__ __forceinline__ float fdot2(unsigned h, unsigned w, float c) {
  return __builtin_amdgcn_fdot2(__builtin_bit_cast(half2v, h),
                                __builtin_bit_cast(half2v, w), c, false);
}
// v += row_ror<CTRL>(v): cross-lane butterfly add within a 16-lane DPP row.
// 0x128 = row_ror:8, 0x124 = row_ror:4. Commutative f32 adds -> all 4
// K-quarter replicas of a unit end up with bitwise-identical sums.
template <int CTRL>
static __device__ __forceinline__ float dppadd(float v) {
  int t = __builtin_amdgcn_update_dpp(0, __builtin_bit_cast(int, v),
                                      CTRL, 0xF, 0xF, false);
  return v + __builtin_bit_cast(float, t);
}

// One block per batch element (256 blocks = 1/CU). 512 threads = 8 waves
// (2/SIMD). Recurrence GEMV runs on v_dot2_f32_f16 (full-rate VALU, 128
// useful MACs/instr) instead of MFMA (which wasted 15/16 of its columns on a
// single-vector GEMV and serialized 621cy/step of matrix-pipe time). Each
// lane owns one h-unit's 4 gate rows over a 32-wide K-quarter; DPP row_ror
// butterflies reduce the K-quarters in-register, so the per-step critical
// path is pure VALU + one LDS h-exchange + one barrier.
__global__ __attribute__((amdgpu_flat_work_group_size(512, 512),
                          amdgpu_waves_per_eu(2, 2)))
void lstm_dot2(
    const float* __restrict__ x,   const float* __restrict__ Wih,
    const float* __restrict__ Whh, const float* __restrict__ bih,
    const float* __restrict__ bhh, const float* __restrict__ Wo,
    const float* __restrict__ bo,  float* __restrict__ out)
{
  __shared__ unsigned       xs[CH][68];          // x chunk, f16 pairs (+4 pad)
  __shared__ unsigned short xgf[CH][XGP];        // xg preact (scaled, +bias, /4), f16
  __shared__ __align__(16) unsigned hbuf[2][64]; // h ping-pong, f16 pairs

  const int tid  = threadIdx.x;
  const int b    = blockIdx.x;
  const int lane = tid & 63;
  const int wv   = tid >> 6;
  const int quad = lane >> 4;
  const int m16  = lane & 15;
  const int unit_l = quad * 4 + (m16 & 3);   // unit within wave, 0..15
  const int unit_g = wv * 16 + unit_l;       // global h-unit, 0..127
  const int kq   = m16 >> 2;                 // K-quarter, 0..3

  // ---- Whh dot-fragments, pre-scaled, persistent:
  // wd[g][p] = f16 pair of Whh_s[g*128+unit_g][kq*32 + 2p .. 2p+1]
  unsigned wd[4][16];
  #pragma unroll
  for (int g = 0; g < 4; ++g) {
    float s = (g == 2) ? LOG2E2 : NLOG2E;
    const float4* p =
        (const float4*)(Whh + (size_t)(g * 128 + unit_g) * H_) + kq * 8;
    #pragma unroll
    for (int q = 0; q < 8; ++q) {
      float4 f = p[q];
      wd[g][q * 2]     = pkh(f.x * s, f.y * s);
      wd[g][q * 2 + 1] = pkh(f.z * s, f.w * s);
    }
  }

  // ---- Wih B-fragments for the input GEMM, pre-scaled by gate type (= wv>>1)
  const float sW = ((wv >> 1) == 2) ? LOG2E2 : NLOG2E;
  uint4 wb[4][4];
  float bv[4];
  #pragma unroll
  for (int nt = 0; nt < 4; ++nt) {
    int gcol = wv * 64 + nt * 16 + m16;
    const float4* p = (const float4*)(Wih + (size_t)gcol * D_);
    #pragma unroll
    for (int kf = 0; kf < 4; ++kf) {
      float4 f0 = p[kf * 8 + quad * 2];
      float4 f1 = p[kf * 8 + quad * 2 + 1];
      uint4 u;
      u.x = pkh(f0.x * sW, f0.y * sW);  u.y = pkh(f0.z * sW, f0.w * sW);
      u.z = pkh(f1.x * sW, f1.y * sW);  u.w = pkh(f1.z * sW, f1.w * sW);
      wb[nt][kf] = u;
    }
    bv[nt] = (bih[gcol] + bhh[gcol]) * sW;
  }

  if (tid < 128) hbuf[tid >> 6][tid & 63] = 0u;
  const floatx4 zf = {0.f, 0.f, 0.f, 0.f};
  float c = 0.0f;
  __syncthreads();

  const float* xb = x + (size_t)b * T_ * D_;

  for (int ch = 0; ch < NCH; ++ch) {
    // ---- stage x chunk (16 KB) as f16 pairs
    const float4* xsrc = (const float4*)(xb + (size_t)ch * CH * D_);
    #pragma unroll
    for (int i = 0; i < 2; ++i) {
      int fi = i * 512 + tid;
      float4 v = xsrc[fi];
      int t  = fi >> 5;
      int kp = (fi & 31) * 2;
      xs[t][kp]     = pkh(v.x, v.y);
      xs[t][kp + 1] = pkh(v.z, v.w);
    }
    __syncthreads();

    // ---- xg chunk: [32 t] x [512 g] = xs @ Wih_s^T (+ scaled bias), f16 out.
    // Stored pre-divided by 4: the recurrence sums 4 K-quarter replicas that
    // each seed their accumulator with xg/4 (exponent shift -> exact).
    #pragma unroll
    for (int mt = 0; mt < 2; ++mt) {
      half8v af[4];
      #pragma unroll
      for (int kf = 0; kf < 4; ++kf)
        af[kf] = __builtin_bit_cast(half8v,
                   *(const uint4*)&xs[mt * 16 + m16][kf * 16 + quad * 4]);
      #pragma unroll
      for (int nt = 0; nt < 4; ++nt) {
        floatx4 acc = zf;
        #pragma unroll
        for (int kf = 0; kf < 4; ++kf)
          acc = __builtin_amdgcn_mfma_f32_16x16x32_f16(
              af[kf], __builtin_bit_cast(half8v, wb[nt][kf]), acc, 0, 0, 0);
        int gcol = wv * 64 + nt * 16 + m16;
        int jc   = gcol & 127, gt = gcol >> 7;
        #pragma unroll
        for (int r = 0; r < 4; ++r) {
          int trow = mt * 16 + quad * 4 + r;
          xgf[trow][jc * 4 + gt] =
              __half_as_ushort(__float2half((acc[r] + bv[nt]) * 0.25f));
        }
      }
    }
    __syncthreads();

    // ---- 32 recurrence steps (pure VALU GEMV + in-register K reduction)
    #pragma unroll 2
    for (int tt = 0; tt < CH; ++tt) {
      const int rp = tt & 1;
      // xg seed: 4 gates of this lane's unit (broadcast across kq replicas)
      unsigned long long xv =
          *(const unsigned long long*)&xgf[tt][unit_g * 4];
      // h slice for this lane's K-quarter: 32 halves = 16 pairs
      const unsigned* hb = &hbuf[rp][kq * 16];
      unsigned hs[16];
      *(uint4*)&hs[0]  = *(const uint4*)(hb + 0);
      *(uint4*)&hs[4]  = *(const uint4*)(hb + 4);
      *(uint4*)&hs[8]  = *(const uint4*)(hb + 8);
      *(uint4*)&hs[12] = *(const uint4*)(hb + 12);
      unsigned xlo = (unsigned)xv, xhi = (unsigned)(xv >> 32);
      float ai = h2f_lo(xlo), af_ = h2f_hi(xlo);
      float ag = h2f_lo(xhi), ao  = h2f_hi(xhi);
      #pragma unroll
      for (int p = 0; p < 16; ++p) {
        ai  = fdot2(hs[p], wd[0][p], ai);
        af_ = fdot2(hs[p], wd[1][p], af_);
        ag  = fdot2(hs[p], wd[2][p], ag);
        ao  = fdot2(hs[p], wd[3][p], ao);
      }
      // reduce the 4 K-quarters (lanes m16 = x, x+4, x+8, x+12)
      ai  = dppadd<0x124>(dppadd<0x128>(ai));
      af_ = dppadd<0x124>(dppadd<0x128>(af_));
      ag  = dppadd<0x124>(dppadd<0x128>(ag));
      ao  = dppadd<0x124>(dppadd<0x128>(ao));
      // activations (all lanes; replicas carry identical values)
      float gi = __builtin_amdgcn_rcpf(1.0f + __builtin_amdgcn_exp2f(ai));
      float gf = __builtin_amdgcn_rcpf(1.0f + __builtin_amdgcn_exp2f(af_));
      float go = __builtin_amdgcn_rcpf(1.0f + __builtin_amdgcn_exp2f(ao));
      float gg = 1.0f - 2.0f * __builtin_amdgcn_rcpf(
                     1.0f + __builtin_amdgcn_exp2f(ag));
      c = gf * c + gi * gg;
      float tc = 1.0f - 2.0f * __builtin_amdgcn_rcpf(
                     1.0f + __builtin_amdgcn_exp2f(c * LOG2E2));
      float h = go * tc;
      if (m16 < 4)   // kq==0 replica writes its unit
        ((unsigned short*)hbuf[rp ^ 1])[unit_g] =
            __half_as_ushort(__float2half(h));
      __syncthreads();
    }
  }

  // ---- out = h_last @ Wo^T + bo   (h_last in hbuf[0]: last step wrote buf 0)
  if (tid < H_) {
    float acc = bo[tid];
    const float4* wr = (const float4*)(Wo + (size_t)tid * H_);
    const uint2* hp = (const uint2*)hbuf[0];
    #pragma unroll
    for (int k4 = 0; k4 < 32; ++k4) {
      float4 w  = wr[k4];
      uint2  hu = hp[k4];
      acc += w.x * h2f_lo(hu.x) + w.y * h2f_hi(hu.x)
           + w.z * h2f_lo(hu.y) + w.w * h2f_hi(hu.y);
    }
    out[(size_t)b * H_ + tid] = acc;
  }
}

extern "C" void kernel_launch(void* const* d_in, const int* in_sizes, int n_in,
                              void* d_out, int out_size, void* d_ws, size_t ws_size,
                              hipStream_t stream) {
  (void)in_sizes; (void)n_in; (void)d_ws; (void)ws_size; (void)out_size;
  const float* x   = (const float*)d_in[0];
  const float* Wih = (const float*)d_in[1];
  const float* Whh = (const float*)d_in[2];
  const float* bih = (const float*)d_in[3];
  const float* bhh = (const float*)d_in[4];
  const float* Wo  = (const float*)d_in[5];
  const float* bo  = (const float*)d_in[6];
  lstm_dot2<<<B_, 512, 0, stream>>>(x, Wih, Whh, bih, bhh, Wo, bo, (float*)d_out);
}